// Round 3
// baseline (6334.923 us; speedup 1.0000x reference)
//
#include <hip/hip_runtime.h>
#include <hip/hip_cooperative_groups.h>
#include <math.h>

namespace cg = cooperative_groups;

#define NTOKEN 15000
#define EMBED  1024
#define HID    1024
#define VDIM   2048
#define MAXLEN 20
#define BATCH  128
#define NOBJ   36
#define TSTEP  19

typedef unsigned short ushort_t;
typedef __attribute__((ext_vector_type(8))) short short8;
typedef __attribute__((ext_vector_type(4))) float floatx4;

__device__ __forceinline__ float b2f(ushort_t u) {
    return __uint_as_float(((unsigned)u) << 16);
}
__device__ __forceinline__ ushort_t f2b(float f) {
    unsigned x = __float_as_uint(f);
    unsigned r = (x + 0x7fffu + ((x >> 16) & 1u)) >> 16;
    return (ushort_t)r;
}

// ---------------------------------------------------------------------------
// MFMA bf16 GEMM core: C[crow?[m]][n] = post( A[arow?[m]] @ B^T )
//   post: +bias[n], +cadd[(m/cadd_div)*ldadd+n], relu if n<relu_n, *mulvec[n]
// BM = 128 (M % 128 == 0), BN = NF*16, K % 32 == 0. N guarded.
// LDS stride 40 (80 B) -> conflict-free ds_read_b128.
// ---------------------------------------------------------------------------
template<int NF, bool OUT_BF16>
__device__ __forceinline__ void mfma_core(
    ushort_t* As, ushort_t* Bs,
    const ushort_t* __restrict__ A, int lda, const int* __restrict__ arow,
    const ushort_t* __restrict__ B, int ldb,
    void* __restrict__ Cv, int ldc, const int* __restrict__ crow,
    const float* __restrict__ bias, const float* __restrict__ mulvec,
    const float* __restrict__ cadd, long ldadd, int cadd_div,
    int relu_n, int N, int K, int m0, int n0)
{
    const int tid  = threadIdx.x;
    const int lane = tid & 63;
    const int w    = tid >> 6;

    floatx4 acc[2][NF];
#pragma unroll
    for (int mf = 0; mf < 2; mf++)
#pragma unroll
        for (int nf = 0; nf < NF; nf++) acc[mf][nf] = (floatx4){0.f, 0.f, 0.f, 0.f};

    const int a_r = tid >> 1;
    const int a_c = (tid & 1) * 16;
    int a_g = m0 + a_r;
    if (arow) a_g = arow[a_g];
    const ushort_t* Aptr = A + (long)a_g * lda + a_c;

    int b_r, b_c;
    if (NF == 8) { b_r = tid >> 1; b_c = (tid & 1) * 16; }
    else         { b_r = tid >> 2; b_c = (tid & 3) * 8;  }
    int b_g = n0 + b_r;
    if (b_g >= N) b_g = N - 1;
    const ushort_t* Bptr = B + (long)b_g * ldb + b_c;

    uint4 av0 = *(const uint4*)(Aptr);
    uint4 av1 = *(const uint4*)(Aptr + 8);
    uint4 bv0 = *(const uint4*)(Bptr);
    uint4 bv1;
    if (NF == 8) bv1 = *(const uint4*)(Bptr + 8);

    const int fr = lane & 15;
    const int q8 = (lane >> 4) * 8;

    for (int kk = 0; kk < K; kk += 32) {
        __syncthreads();
        *(uint4*)(As + a_r * 40 + a_c)     = av0;
        *(uint4*)(As + a_r * 40 + a_c + 8) = av1;
        *(uint4*)(Bs + b_r * 40 + b_c)     = bv0;
        if (NF == 8) *(uint4*)(Bs + b_r * 40 + b_c + 8) = bv1;
        if (kk + 32 < K) {
            av0 = *(const uint4*)(Aptr + kk + 32);
            av1 = *(const uint4*)(Aptr + kk + 40);
            bv0 = *(const uint4*)(Bptr + kk + 32);
            if (NF == 8) bv1 = *(const uint4*)(Bptr + kk + 40);
        }
        __syncthreads();
        short8 bfrag[NF];
#pragma unroll
        for (int nf = 0; nf < NF; nf++)
            bfrag[nf] = *(const short8*)(Bs + (nf * 16 + fr) * 40 + q8);
#pragma unroll
        for (int mf = 0; mf < 2; mf++) {
            short8 afrag = *(const short8*)(As + (w * 32 + mf * 16 + fr) * 40 + q8);
#pragma unroll
            for (int nf = 0; nf < NF; nf++)
                acc[mf][nf] = __builtin_amdgcn_mfma_f32_16x16x32_bf16(
                    afrag, bfrag[nf], acc[mf][nf], 0, 0, 0);
        }
    }

    const int rq = lane >> 4;
#pragma unroll
    for (int mf = 0; mf < 2; mf++) {
#pragma unroll
        for (int r = 0; r < 4; r++) {
            int m = m0 + w * 32 + mf * 16 + rq * 4 + r;
            int cm = crow ? crow[m] : m;
            const float* caddrow = cadd ? (cadd + (long)(m / cadd_div) * ldadd) : nullptr;
#pragma unroll
            for (int nf = 0; nf < NF; nf++) {
                int n = n0 + nf * 16 + fr;
                if (n < N) {
                    float val = acc[mf][nf][r];
                    if (bias)    val += bias[n];
                    if (caddrow) val += caddrow[n];
                    if (n < relu_n) val = fmaxf(val, 0.f);
                    if (mulvec)  val *= mulvec[n];
                    if (OUT_BF16) ((ushort_t*)Cv)[(long)cm * ldc + n] = f2b(val);
                    else          ((float*)Cv)[(long)cm * ldc + n]   = val;
                }
            }
        }
    }
}

template<int NF, bool OUT_BF16>
__global__ __launch_bounds__(256) void mfma_gemm(
    const ushort_t* __restrict__ A, int lda, const int* __restrict__ arow,
    const ushort_t* __restrict__ B, int ldb,
    void* __restrict__ C, int ldc, const int* __restrict__ crow,
    const float* __restrict__ bias, const float* __restrict__ mulvec,
    const float* __restrict__ cadd, long ldadd, int cadd_div,
    int relu_n, int N, int K)
{
    __shared__ ushort_t As[128 * 40];
    __shared__ ushort_t Bs[(NF > 4 ? 128 : 64) * 40];
    mfma_core<NF, OUT_BF16>(As, Bs, A, lda, arow, B, ldb, C, ldc, crow,
                            bias, mulvec, cadd, ldadd, cadd_div, relu_n,
                            N, K, blockIdx.y * 128, blockIdx.x * (NF * 16));
}

// ---------------------------------------------------------------------------
// Persistent cooperative kernel: the whole 19-step recurrence.
// ---------------------------------------------------------------------------
struct LoopParams {
    const ushort_t* Wih1h; const ushort_t* Whh1b; const ushort_t* Whh2b;
    const ushort_t* Wcat2; const ushort_t* Wih2v; const ushort_t* vw_bf;
    const float* gi1s; const float* bhh1; const float* bhh2; const float* bcat2;
    const float* v; const int* cap_len;
    float* gi; float* gh; float* gh2; float* qgi2;
    float* h1; float* h2;
    ushort_t* h1b; ushort_t* h2b; ushort_t* x2v; ushort_t* H2Ab;
    float* alpha;
};

__device__ __forceinline__ void gru_elem(
    const float* __restrict__ gi, const float* __restrict__ gh,
    float* __restrict__ h, ushort_t* __restrict__ hb,
    ushort_t* __restrict__ hstore, int t, int idx)
{
    int b = idx >> 10, j = idx & (HID - 1);
    const float* gib = gi + (long)b * 3 * HID;
    const float* ghb = gh + (long)b * 3 * HID;
    float ir = gib[j], iz = gib[HID + j], in_ = gib[2 * HID + j];
    float hr = ghb[j], hz = ghb[HID + j], hn  = ghb[2 * HID + j];
    float r = 1.f / (1.f + expf(-(ir + hr)));
    float z = 1.f / (1.f + expf(-(iz + hz)));
    float n = tanhf(in_ + r * hn);
    float hnew = (1.f - z) * n + z * h[idx];
    h[idx] = hnew;
    ushort_t hq = f2b(hnew);
    hb[idx] = hq;
    if (hstore) hstore[((long)(b * TSTEP + t) << 10) | j] = hq;
}

__global__ __launch_bounds__(256) void loop_kernel(LoopParams p)
{
    cg::grid_group grid = cg::this_grid();
    __shared__ ushort_t As[128 * 40];
    __shared__ ushort_t Bs[64 * 40];
    __shared__ float att_s[NOBJ];

    const int tid  = threadIdx.x;
    const int bid  = blockIdx.x;
    const int lane = tid & 63;
    const int w    = tid >> 6;
    const int gtid = bid * 256 + tid;
    const int gsz  = gridDim.x * 256;

    for (int t = 0; t < TSTEP; t++) {
        // ---- Phase A: gi1 / gh1 / gh2 (3 x [128 x 3072], K=1024), 144 tiles of 128x64
        if (bid < 144) {
            int mat = bid / 48;
            int n0  = (bid % 48) * 64;
            const ushort_t* A = (mat == 1) ? p.h1b : p.h2b;
            const ushort_t* B = (mat == 0) ? p.Wih1h : (mat == 1 ? p.Whh1b : p.Whh2b);
            float* C          = (mat == 0) ? p.gi    : (mat == 1 ? p.gh    : p.gh2);
            const float* bias = (mat == 0) ? nullptr : (mat == 1 ? p.bhh1  : p.bhh2);
            const float* cadd = (mat == 0) ? (p.gi1s + (long)t * 3072) : nullptr;
            mfma_core<4, false>(As, Bs, A, 1024, nullptr, B, 1024, C, 3072, nullptr,
                                bias, nullptr, cadd, (long)TSTEP * 3072, 1, 0,
                                3072, 1024, 0, n0);
        }
        grid.sync();

        // ---- GRU1: h1 = gru(gi, gh, h1)
        for (int i = gtid; i < BATCH * HID; i += gsz)
            gru_elem(p.gi, p.gh, p.h1, p.h1b, nullptr, t, i);
        grid.sync();

        // ---- Phase B: [q | gi2_h] = h1b @ Wcat2^T + bcat2, relu first 1024 cols
        if (bid < 128)
            mfma_core<2, false>(As, Bs, p.h1b, 1024, nullptr, p.Wcat2, 1024,
                                p.qgi2, 4096, nullptr, p.bcat2, nullptr,
                                nullptr, 0, 1, 1024, 4096, 1024, 0, bid * 32);
        grid.sync();

        // ---- Attention: 2 blocks per batch element
        {
            int b = bid >> 1, half = bid & 1;
            const float* qb = p.qgi2 + (long)b * 4096;
            for (int o = w; o < NOBJ; o += 4) {
                const ushort_t* vwo = p.vw_bf + ((long)b * NOBJ + o) * HID;
                float s = 0.f;
                for (int hh = lane; hh < HID; hh += 64) s += b2f(vwo[hh]) * qb[hh];
                for (int off = 32; off > 0; off >>= 1) s += __shfl_down(s, off);
                if (lane == 0) att_s[o] = s;
            }
            __syncthreads();
            if (tid == 0) {
                float mx = att_s[0];
                for (int o = 1; o < NOBJ; o++) mx = fmaxf(mx, att_s[o]);
                float sum = 0.f;
                for (int o = 0; o < NOBJ; o++) { float e = expf(att_s[o] - mx); att_s[o] = e; sum += e; }
                float inv = 1.f / sum;
                for (int o = 0; o < NOBJ; o++) att_s[o] *= inv;
            }
            __syncthreads();
            bool m = (t < p.cap_len[b] - 1);
            if (half == 0 && tid < NOBJ)
                p.alpha[((long)b * MAXLEN + t) * NOBJ + tid] = m ? att_s[tid] : 0.f;
            for (int d = half * 1024 + tid; d < half * 1024 + 1024; d += 256) {
                float s = 0.f;
                for (int o = 0; o < NOBJ; o++)
                    s += att_s[o] * p.v[((long)b * NOBJ + o) * VDIM + d];
                p.x2v[(long)b * VDIM + d] = f2b(s);
            }
        }
        grid.sync();

        // ---- Phase C: gi2 = x2v @ Wih2v^T + gi2_h (K=2048), 96 tiles of 128x32
        if (bid < 96)
            mfma_core<2, false>(As, Bs, p.x2v, 2048, nullptr, p.Wih2v, 2048,
                                p.gi, 3072, nullptr, nullptr, nullptr,
                                p.qgi2 + 1024, 4096, 1, 0, 3072, 2048, 0, bid * 32);
        grid.sync();

        // ---- GRU2: h2 = gru(gi, gh2, h2), store into H2Ab
        for (int i = gtid; i < BATCH * HID; i += gsz)
            gru_elem(p.gi, p.gh2, p.h2, p.h2b, p.H2Ab, t, i);
        grid.sync();
    }
}

// ---------------------------------------------------------------------------
// small helper kernels
// ---------------------------------------------------------------------------
__global__ void init_kernel(const int* __restrict__ caption,
                            int* __restrict__ tok_idx, int* __restrict__ crow20,
                            float* __restrict__ h12f, ushort_t* __restrict__ h12b)
{
    int idx = blockIdx.x * 256 + threadIdx.x;
    if (idx < BATCH * TSTEP) {
        int b = idx / TSTEP, t = idx % TSTEP;
        tok_idx[idx] = caption[b * MAXLEN + t];
        crow20[idx]  = b * MAXLEN + t;
    }
    h12f[idx] = 0.f;
    h12b[idx] = 0;
}

__global__ void sort_caption_kernel(const int* __restrict__ caption,
                                    const int* __restrict__ cap_len,
                                    float* __restrict__ out1)
{
    int i = threadIdx.x;
    if (i < BATCH) {
        int li = cap_len[i];
        int rank = 0;
        for (int j = 0; j < BATCH; j++) {
            int lj = cap_len[j];
            if (lj > li || (lj == li && j < i)) rank++;
        }
        for (int k = 0; k < TSTEP; k++)
            out1[rank * TSTEP + k] = (float)caption[i * MAXLEN + 1 + k];
    }
}

__global__ void vmean_kernel(const float* __restrict__ v,
                             float* __restrict__ vmean, ushort_t* __restrict__ vmeanb)
{
    int idx = blockIdx.x * 256 + threadIdx.x;
    int b = idx >> 11, d = idx & (VDIM - 1);
    float s = 0.f;
    for (int o = 0; o < NOBJ; o++) s += v[((long)b * NOBJ + o) * VDIM + d];
    float m = s * (1.0f / 36.0f);
    vmean[idx] = m;
    vmeanb[idx] = f2b(m);
}

__global__ void conv_kernel(const float* __restrict__ src, long ld,
                            const int* __restrict__ rowidx,
                            ushort_t* __restrict__ dst, int rows, int cols)
{
    long idx4 = ((long)blockIdx.x * 256 + threadIdx.x) * 4;
    if (idx4 >= (long)rows * cols) return;
    int r = (int)(idx4 / cols);
    int c = (int)(idx4 % cols);
    long sr = rowidx ? rowidx[r] : r;
    float4 f = *(const float4*)(src + sr * ld + c);
    dst[idx4 + 0] = f2b(f.x);
    dst[idx4 + 1] = f2b(f.y);
    dst[idx4 + 2] = f2b(f.z);
    dst[idx4 + 3] = f2b(f.w);
}

__global__ void transpose_conv_kernel(const float* __restrict__ src,
                                      ushort_t* __restrict__ dst)
{
    __shared__ float tile[32][33];
    int bx = blockIdx.x, by = blockIdx.y;
    int lx = threadIdx.x & 31, ly = threadIdx.x >> 5;
    for (int i = 0; i < 32; i += 8)
        tile[ly + i][lx] = src[(long)(by * 32 + ly + i) * 1024 + bx * 32 + lx];
    __syncthreads();
    for (int i = 0; i < 32; i += 8)
        dst[(long)(bx * 32 + ly + i) * 1024 + by * 32 + lx] = f2b(tile[lx][ly + i]);
}

__global__ void bias_fold_kernel(const float* __restrict__ Wq,
                                 const float* __restrict__ Wih2,
                                 const float* __restrict__ bfc1,
                                 const float* __restrict__ bq,
                                 const float* __restrict__ bih2,
                                 float* __restrict__ bcat2)
{
    int wave = blockIdx.x * 4 + (threadIdx.x >> 6);
    int lane = threadIdx.x & 63;
    for (int n = wave; n < 4096; n += 256) {
        const float* wrow = (n < 1024) ? (Wq + (long)n * 1024)
                                       : (Wih2 + (long)(n - 1024) * 3072 + 2048);
        float s = 0.f;
        for (int j = lane; j < 1024; j += 64) s += wrow[j] * bfc1[j];
        for (int off = 32; off > 0; off >>= 1) s += __shfl_down(s, off);
        if (lane == 0) bcat2[n] = s + ((n < 1024) ? bq[n] : bih2[n - 1024]);
    }
}

__global__ __launch_bounds__(256) void softmax_kernel(float* __restrict__ predict,
                                                      float* __restrict__ alpha,
                                                      const int* __restrict__ cap_len)
{
    __shared__ float sred[4];
    int row = blockIdx.x;
    int b = row / MAXLEN, t = row % MAXLEN;
    float* p = predict + (long)row * NTOKEN;
    int tid = threadIdx.x;
    int dec = cap_len[b] - 1;
    if (t >= dec) {
        const float u = 1.0f / (float)NTOKEN;
        for (int i = tid; i < NTOKEN; i += 256) p[i] = u;
        if (t == MAXLEN - 1 && tid < NOBJ) alpha[(long)row * NOBJ + tid] = 0.f;
        return;
    }
    float mx = -3.4e38f;
    for (int i = tid; i < NTOKEN; i += 256) mx = fmaxf(mx, p[i]);
    for (int off = 32; off > 0; off >>= 1) mx = fmaxf(mx, __shfl_down(mx, off));
    if ((tid & 63) == 0) sred[tid >> 6] = mx;
    __syncthreads();
    mx = fmaxf(fmaxf(sred[0], sred[1]), fmaxf(sred[2], sred[3]));
    __syncthreads();
    float s = 0.f;
    for (int i = tid; i < NTOKEN; i += 256) s += expf(p[i] - mx);
    for (int off = 32; off > 0; off >>= 1) s += __shfl_down(s, off);
    if ((tid & 63) == 0) sred[tid >> 6] = s;
    __syncthreads();
    s = sred[0] + sred[1] + sred[2] + sred[3];
    float inv = 1.f / s;
    for (int i = tid; i < NTOKEN; i += 256) p[i] = expf(p[i] - mx) * inv;
}

// ---------------------------------------------------------------------------
extern "C" void kernel_launch(void* const* d_in, const int* in_sizes, int n_in,
                              void* d_out, int out_size, void* d_ws, size_t ws_size,
                              hipStream_t stream)
{
    const float* v       = (const float*)d_in[0];
    const int*   caption = (const int*)  d_in[1];
    const int*   cap_len = (const int*)  d_in[2];
    const float* emb     = (const float*)d_in[3];
    const float* Wih1    = (const float*)d_in[4];
    const float* Whh1    = (const float*)d_in[5];
    const float* bih1    = (const float*)d_in[6];
    const float* bhh1    = (const float*)d_in[7];
    const float* Wih2    = (const float*)d_in[8];
    const float* Whh2    = (const float*)d_in[9];
    const float* bih2    = (const float*)d_in[10];
    const float* bhh2    = (const float*)d_in[11];
    const float* Wfc1    = (const float*)d_in[12];
    const float* bfc1    = (const float*)d_in[13];
    const float* Wfc2    = (const float*)d_in[14];
    const float* bfc2    = (const float*)d_in[15];
    const float* Wv      = (const float*)d_in[16];
    const float* bv      = (const float*)d_in[17];
    const float* Wq      = (const float*)d_in[18];
    const float* bq      = (const float*)d_in[19];
    const float* Wa      = (const float*)d_in[20];
    // ba cancels in softmax

    float* f32base = (float*)d_ws;
    float* gvm   = f32base;              // 128*3072
    float* gi1s  = gvm   + 393216;       // 2432*3072
    float* h1    = gi1s  + 7471104;      // 128*1024 (h1,h2 contiguous for init)
    float* h2    = h1    + 131072;
    float* gi    = h2    + 131072;       // 128*3072
    float* gh    = gi    + 393216;
    float* gh2   = gh    + 393216;
    float* qgi2  = gh2   + 393216;       // 128*4096
    float* vmean = qgi2  + 524288;       // 128*2048
    float* bcat2 = vmean + 262144;       // 4096
    ushort_t* ub = (ushort_t*)(bcat2 + 4096);
    ushort_t* Wih1h = ub;                 // 3072*1024
    ushort_t* Wih1c = Wih1h + 3145728;
    ushort_t* Whh1b = Wih1c + 3145728;
    ushort_t* Whh2b = Whh1b + 3145728;
    ushort_t* Wih2v = Whh2b + 3145728;    // 3072*2048
    ushort_t* Wcat2 = Wih2v + 6291456;    // 4096*1024
    ushort_t* Wfc2b = Wcat2 + 4194304;    // 15000*1024
    ushort_t* vw_bf = Wfc2b + 15360000;   // 4608*1024
    ushort_t* H2Ab  = vw_bf + 4718592;    // 2432*1024
    ushort_t* h1b   = H2Ab  + 2490368;    // (h1b,h2b contiguous for init)
    ushort_t* h2b   = h1b   + 131072;
    ushort_t* x2v   = h2b   + 131072;     // 128*2048
    ushort_t* vmeanb= x2v   + 262144;     // 128*2048
    ushort_t* TEMP  = vmeanb+ 262144;
    ushort_t* vb     = TEMP;              // 4608*2048
    ushort_t* Wvb    = TEMP + 9437184;    // 1024*2048
    ushort_t* Wqb    = TEMP;              // 1024*1024
    ushort_t* Wih2hb = TEMP + 1048576;    // 3072*1024
    ushort_t* Wfc1T  = TEMP + 4194304;    // 1024*1024
    ushort_t* Wih1m  = TEMP;              // 3072*2048
    ushort_t* Acap   = TEMP;              // 2432*1024
    int* tok_idx = (int*)(TEMP + 11534336);
    int* crow20  = tok_idx + BATCH * TSTEP;

    float* out     = (float*)d_out;
    float* predict = out;                                   // 128*20*15000
    float* out1    = out + (long)BATCH * MAXLEN * NTOKEN;   // 128*19
    float* alpha   = out1 + (long)BATCH * TSTEP;            // 128*20*36

    #define CONV(src, ld, rowidx, dst, rows, cols) \
        conv_kernel<<<(int)(((long)(rows)*(cols)/4 + 255)/256), 256, 0, stream>>>( \
            src, ld, rowidx, dst, rows, cols)

    // ---- prologue ----
    init_kernel<<<1024, 256, 0, stream>>>(caption, tok_idx, crow20, h1, h1b);
    sort_caption_kernel<<<1, 128, 0, stream>>>(caption, cap_len, out1);
    vmean_kernel<<<(BATCH * VDIM) / 256, 256, 0, stream>>>(v, vmean, vmeanb);

    CONV(Wih1,        4096, nullptr, Wih1h, 3072, 1024);
    CONV(Wih1 + 3072, 4096, nullptr, Wih1c, 3072, 1024);
    CONV(Whh1,        1024, nullptr, Whh1b, 3072, 1024);
    CONV(Whh2,        1024, nullptr, Whh2b, 3072, 1024);
    CONV(Wih2,        3072, nullptr, Wih2v, 3072, 2048);
    CONV(Wfc2,        1024, nullptr, Wfc2b, NTOKEN, 1024);

    // vw = relu(v @ Wv^T + bv) * Wa -> bf16 [4608 x 1024]
    CONV(v,  2048, nullptr, vb,  4608, 2048);
    CONV(Wv, 2048, nullptr, Wvb, 1024, 2048);
    mfma_gemm<8, true><<<dim3(8, 36), 256, 0, stream>>>(
        vb, 2048, nullptr, Wvb, 2048, vw_bf, 1024, nullptr,
        bv, Wa, nullptr, 0, 1, 1024, 1024, 2048);

    // folded weights: Wcat2 = [Wq@Wfc1 ; Wih2[:,2048:]@Wfc1]
    CONV(Wq,          1024, nullptr, Wqb,    1024, 1024);
    CONV(Wih2 + 2048, 3072, nullptr, Wih2hb, 3072, 1024);
    transpose_conv_kernel<<<dim3(32, 32), 256, 0, stream>>>(Wfc1, Wfc1T);
    mfma_gemm<8, true><<<dim3(8, 8), 256, 0, stream>>>(
        Wqb, 1024, nullptr, Wfc1T, 1024, Wcat2, 1024, nullptr,
        nullptr, nullptr, nullptr, 0, 1, 0, 1024, 1024);
    mfma_gemm<8, true><<<dim3(8, 24), 256, 0, stream>>>(
        Wih2hb, 1024, nullptr, Wfc1T, 1024, Wcat2 + 1048576, 1024, nullptr,
        nullptr, nullptr, nullptr, 0, 1, 0, 1024, 1024);
    bias_fold_kernel<<<64, 256, 0, stream>>>(Wq, Wih2, bfc1, bq, bih2, bcat2);

    // gvm = vmean @ Wih1[:,1024:3072]^T + bih1
    CONV(Wih1 + 1024, 4096, nullptr, Wih1m, 3072, 2048);
    mfma_gemm<8, false><<<dim3(24, 1), 256, 0, stream>>>(
        vmeanb, 2048, nullptr, Wih1m, 2048, gvm, 3072, nullptr,
        bih1, nullptr, nullptr, 0, 1, 0, 3072, 2048);

    // gi1s[b*19+t] = emb[cap[b,t]] @ Wih1[:,3072:]^T + gvm[b]
    CONV(emb, 1024, tok_idx, Acap, 2432, 1024);
    mfma_gemm<8, false><<<dim3(24, 19), 256, 0, stream>>>(
        Acap, 1024, nullptr, Wih1c, 1024, gi1s, 3072, nullptr,
        nullptr, nullptr, gvm, 3072, TSTEP, 0, 3072, 1024);

    // ---- recurrent loop: one persistent cooperative kernel ----
    LoopParams p;
    p.Wih1h = Wih1h; p.Whh1b = Whh1b; p.Whh2b = Whh2b;
    p.Wcat2 = Wcat2; p.Wih2v = Wih2v; p.vw_bf = vw_bf;
    p.gi1s = gi1s; p.bhh1 = bhh1; p.bhh2 = bhh2; p.bcat2 = bcat2;
    p.v = v; p.cap_len = cap_len;
    p.gi = gi; p.gh = gh; p.gh2 = gh2; p.qgi2 = qgi2;
    p.h1 = h1; p.h2 = h2;
    p.h1b = h1b; p.h2b = h2b; p.x2v = x2v; p.H2Ab = H2Ab;
    p.alpha = alpha;
    void* kargs[] = { &p };
    hipLaunchCooperativeKernel((const void*)loop_kernel, dim3(256), dim3(256),
                               kargs, 0, stream);

    // ---- epilogue ----
    mfma_gemm<8, false><<<dim3(118, 19), 256, 0, stream>>>(
        H2Ab, 1024, nullptr, Wfc2b, 1024, predict, NTOKEN, crow20,
        bfc2, nullptr, nullptr, 0, 1, 0, NTOKEN, 1024);
    softmax_kernel<<<BATCH * MAXLEN, 256, 0, stream>>>(predict, alpha, cap_len);
    #undef CONV
}

// Round 4
// 3934.837 us; speedup vs baseline: 1.6100x; 1.6100x over previous
//
#include <hip/hip_runtime.h>
#include <math.h>

#define NTOKEN 15000
#define EMBED  1024
#define HID    1024
#define VDIM   2048
#define MAXLEN 20
#define BATCH  128
#define NOBJ   36
#define TSTEP  19

typedef unsigned short ushort_t;
typedef __attribute__((ext_vector_type(8))) short short8;
typedef __attribute__((ext_vector_type(4))) float floatx4;

__device__ __forceinline__ float b2f(ushort_t u) {
    return __uint_as_float(((unsigned)u) << 16);
}
__device__ __forceinline__ ushort_t f2b(float f) {
    unsigned x = __float_as_uint(f);
    unsigned r = (x + 0x7fffu + ((x >> 16) & 1u)) >> 16;
    return (ushort_t)r;
}

// ---------------------------------------------------------------------------
// MFMA bf16 GEMM core, depth-2 software pipeline (double-buffered LDS, loads
// issued 2 k-iters ahead, ONE barrier per iter).
//   C[crow?[m]][n] = post( A[arow?[m]] @ B^T )
//   post: +bias[n], +cadd[(m/cadd_div)*ldadd+n], relu if n<relu_n, *mulvec[n]
// BM = 128 (M % 128 == 0), BN = NF*16, K % 32 == 0, K >= 64. N guarded.
// LDS stride 40 elems (80 B). As: 2*128*40, Bs: 2*NF*16*40.
// ---------------------------------------------------------------------------
template<int NF, bool OUT_BF16>
__device__ __forceinline__ void mfma_core(
    ushort_t* As, ushort_t* Bs,
    const ushort_t* __restrict__ A, int lda, const int* __restrict__ arow,
    const ushort_t* __restrict__ B, int ldb,
    void* __restrict__ Cv, int ldc, const int* __restrict__ crow,
    const float* __restrict__ bias, const float* __restrict__ mulvec,
    const float* __restrict__ cadd, long ldadd, int cadd_div,
    int relu_n, int N, int K, int m0, int n0)
{
    constexpr int ABUF = 128 * 40;
    constexpr int BBUF = NF * 16 * 40;
    const int tid  = threadIdx.x;
    const int lane = tid & 63;
    const int w    = tid >> 6;

    floatx4 acc[2][NF];
#pragma unroll
    for (int mf = 0; mf < 2; mf++)
#pragma unroll
        for (int nf = 0; nf < NF; nf++) acc[mf][nf] = (floatx4){0.f, 0.f, 0.f, 0.f};

    const int a_r = tid >> 1;
    const int a_c = (tid & 1) * 16;
    int a_g = m0 + a_r;
    if (arow) a_g = arow[a_g];
    const ushort_t* Aptr = A + (long)a_g * lda + a_c;

    int b_r, b_c;
    if (NF == 8)      { b_r = tid >> 1; b_c = (tid & 1) * 16; }
    else if (NF == 4) { b_r = tid >> 2; b_c = (tid & 3) * 8;  }
    else              { b_r = tid >> 3; b_c = (tid & 7) * 4;  }
    int b_g = n0 + b_r;
    if (b_g >= N) b_g = N - 1;
    const ushort_t* Bptr = B + (long)b_g * ldb + b_c;

    uint4 av0[2], av1[2], bv0[2], bv1[2];
    uint2 b2v[2];
    const int nit = K >> 5;

#pragma unroll
    for (int s = 0; s < 2; s++) {
        int kk = s * 32;
        av0[s] = *(const uint4*)(Aptr + kk);
        av1[s] = *(const uint4*)(Aptr + kk + 8);
        if (NF == 2) b2v[s] = *(const uint2*)(Bptr + kk);
        else {
            bv0[s] = *(const uint4*)(Bptr + kk);
            if (NF == 8) bv1[s] = *(const uint4*)(Bptr + kk + 8);
        }
    }

    const int fr = lane & 15;
    const int q8 = (lane >> 4) * 8;

    for (int i = 0; i < nit; i++) {
        int s = i & 1;
        ushort_t* Asb = As + s * ABUF;
        ushort_t* Bsb = Bs + s * BBUF;
        *(uint4*)(Asb + a_r * 40 + a_c)     = av0[s];
        *(uint4*)(Asb + a_r * 40 + a_c + 8) = av1[s];
        if (NF == 2) *(uint2*)(Bsb + b_r * 40 + b_c) = b2v[s];
        else {
            *(uint4*)(Bsb + b_r * 40 + b_c) = bv0[s];
            if (NF == 8) *(uint4*)(Bsb + b_r * 40 + b_c + 8) = bv1[s];
        }
        if (i + 2 < nit) {
            int kk = (i + 2) * 32;
            av0[s] = *(const uint4*)(Aptr + kk);
            av1[s] = *(const uint4*)(Aptr + kk + 8);
            if (NF == 2) b2v[s] = *(const uint2*)(Bptr + kk);
            else {
                bv0[s] = *(const uint4*)(Bptr + kk);
                if (NF == 8) bv1[s] = *(const uint4*)(Bptr + kk + 8);
            }
        }
        __syncthreads();
        short8 bfrag[NF];
#pragma unroll
        for (int nf = 0; nf < NF; nf++)
            bfrag[nf] = *(const short8*)(Bsb + (nf * 16 + fr) * 40 + q8);
#pragma unroll
        for (int mf = 0; mf < 2; mf++) {
            short8 afrag = *(const short8*)(Asb + (w * 32 + mf * 16 + fr) * 40 + q8);
#pragma unroll
            for (int nf = 0; nf < NF; nf++)
                acc[mf][nf] = __builtin_amdgcn_mfma_f32_16x16x32_bf16(
                    afrag, bfrag[nf], acc[mf][nf], 0, 0, 0);
        }
    }

    const int rq = lane >> 4;
#pragma unroll
    for (int mf = 0; mf < 2; mf++) {
#pragma unroll
        for (int r = 0; r < 4; r++) {
            int m = m0 + w * 32 + mf * 16 + rq * 4 + r;
            int cm = crow ? crow[m] : m;
            const float* caddrow = cadd ? (cadd + (long)(m / cadd_div) * ldadd) : nullptr;
#pragma unroll
            for (int nf = 0; nf < NF; nf++) {
                int n = n0 + nf * 16 + fr;
                if (n < N) {
                    float val = acc[mf][nf][r];
                    if (bias)    val += bias[n];
                    if (caddrow) val += caddrow[n];
                    if (n < relu_n) val = fmaxf(val, 0.f);
                    if (mulvec)  val *= mulvec[n];
                    if (OUT_BF16) ((ushort_t*)Cv)[(long)cm * ldc + n] = f2b(val);
                    else          ((float*)Cv)[(long)cm * ldc + n]   = val;
                }
            }
        }
    }
}

template<int NF, bool OUT_BF16>
__global__ __launch_bounds__(256) void mfma_gemm(
    const ushort_t* __restrict__ A, int lda, const int* __restrict__ arow,
    const ushort_t* __restrict__ B, int ldb,
    void* __restrict__ C, int ldc, const int* __restrict__ crow,
    const float* __restrict__ bias, const float* __restrict__ mulvec,
    const float* __restrict__ cadd, long ldadd, int cadd_div,
    int relu_n, int N, int K)
{
    __shared__ ushort_t As[2 * 128 * 40];
    __shared__ ushort_t Bs[2 * NF * 16 * 40];
    mfma_core<NF, OUT_BF16>(As, Bs, A, lda, arow, B, ldb, C, ldc, crow,
                            bias, mulvec, cadd, ldadd, cadd_div, relu_n,
                            N, K, blockIdx.y * 128, blockIdx.x * (NF * 16));
}

// ---------------------------------------------------------------------------
// Per-step kernels (split-K x2; partials summed in the consumers)
// ---------------------------------------------------------------------------
// gi1/gh1/gh2 trio: grid (48, 2, 3); x: 64-col tile, y: K-half, z: matrix
__global__ __launch_bounds__(256) void trio_kernel(
    const ushort_t* __restrict__ h1b, const ushort_t* __restrict__ h2b,
    const ushort_t* __restrict__ Wih1h, const ushort_t* __restrict__ Whh1b,
    const ushort_t* __restrict__ Whh2b,
    float* __restrict__ gia, float* __restrict__ gib,
    float* __restrict__ gha, float* __restrict__ ghb,
    float* __restrict__ gh2a, float* __restrict__ gh2b,
    const float* __restrict__ gi1s_t,
    const float* __restrict__ bhh1, const float* __restrict__ bhh2)
{
    __shared__ ushort_t As[2 * 128 * 40];
    __shared__ ushort_t Bs[2 * 64 * 40];
    const int mat = blockIdx.z, kh = blockIdx.y, n0 = blockIdx.x * 64;
    const ushort_t* A = ((mat == 1) ? h1b : h2b) + kh * 512;
    const ushort_t* B = ((mat == 0) ? Wih1h : (mat == 1) ? Whh1b : Whh2b) + kh * 512;
    float* C = (mat == 0) ? (kh ? gib : gia)
             : (mat == 1) ? (kh ? ghb : gha)
                          : (kh ? gh2b : gh2a);
    const float* bias = kh ? nullptr : ((mat == 1) ? bhh1 : (mat == 2) ? bhh2 : nullptr);
    const float* cadd = (mat == 0 && kh == 0) ? gi1s_t : nullptr;
    mfma_core<4, false>(As, Bs, A, 1024, nullptr, B, 1024, C, 3072, nullptr,
                        bias, nullptr, cadd, (long)TSTEP * 3072, 1, 0,
                        3072, 512, 0, n0);
}

// qgi2 partials: grid (128, 2); no bias/relu here (applied in consumers)
__global__ __launch_bounds__(256) void qgi2_kernel(
    const ushort_t* __restrict__ h1b, const ushort_t* __restrict__ Wcat2,
    float* __restrict__ qa, float* __restrict__ qb)
{
    __shared__ ushort_t As[2 * 128 * 40];
    __shared__ ushort_t Bs[2 * 32 * 40];
    const int kh = blockIdx.y;
    mfma_core<2, false>(As, Bs, h1b + kh * 512, 1024, nullptr,
                        Wcat2 + kh * 512, 1024, kh ? qb : qa, 4096, nullptr,
                        nullptr, nullptr, nullptr, 0, 1, 0,
                        4096, 512, 0, blockIdx.x * 32);
}

// gi2 partials: grid (96, 2), K=2048 split into 2x1024
__global__ __launch_bounds__(256) void gi2_kernel(
    const ushort_t* __restrict__ x2v, const ushort_t* __restrict__ Wih2v,
    float* __restrict__ ga, float* __restrict__ gb)
{
    __shared__ ushort_t As[2 * 128 * 40];
    __shared__ ushort_t Bs[2 * 32 * 40];
    const int kh = blockIdx.y;
    mfma_core<2, false>(As, Bs, x2v + kh * 1024, 2048, nullptr,
                        Wih2v + kh * 1024, 2048, kh ? gb : ga, 3072, nullptr,
                        nullptr, nullptr, nullptr, 0, 1, 0,
                        3072, 1024, 0, blockIdx.x * 32);
}

// GRU1: h1 = gru(gia+gib, gha+ghb, h1)
__global__ void gru1_kernel(const float* __restrict__ gia, const float* __restrict__ gib,
                            const float* __restrict__ gha, const float* __restrict__ ghb,
                            float* __restrict__ h1, ushort_t* __restrict__ h1b)
{
    int idx = blockIdx.x * 256 + threadIdx.x;
    int b = idx >> 10, j = idx & (HID - 1);
    long o = (long)b * 3072;
    float ir = gia[o + j]        + gib[o + j];
    float iz = gia[o + 1024 + j] + gib[o + 1024 + j];
    float in_= gia[o + 2048 + j] + gib[o + 2048 + j];
    float hr = gha[o + j]        + ghb[o + j];
    float hz = gha[o + 1024 + j] + ghb[o + 1024 + j];
    float hn = gha[o + 2048 + j] + ghb[o + 2048 + j];
    float r = 1.f / (1.f + expf(-(ir + hr)));
    float z = 1.f / (1.f + expf(-(iz + hz)));
    float n = tanhf(in_ + r * hn);
    float hnew = (1.f - z) * n + z * h1[idx];
    h1[idx] = hnew;
    h1b[idx] = f2b(hnew);
}

// GRU2: gate_i = gi2a+gi2b + qgi2a_h+qgi2b_h + bcat2_h ; gate_h = gh2a+gh2b
__global__ void gru2_kernel(const float* __restrict__ g2a, const float* __restrict__ g2b,
                            const float* __restrict__ qa, const float* __restrict__ qb,
                            const float* __restrict__ bch,   // bcat2 + 1024
                            const float* __restrict__ gh2a, const float* __restrict__ gh2b,
                            float* __restrict__ h2, ushort_t* __restrict__ h2b,
                            ushort_t* __restrict__ H2Ab, int t)
{
    int idx = blockIdx.x * 256 + threadIdx.x;
    int b = idx >> 10, j = idx & (HID - 1);
    long o  = (long)b * 3072;
    long oq = (long)b * 4096 + 1024;
    float ir = g2a[o + j]        + g2b[o + j]        + qa[oq + j]        + qb[oq + j]        + bch[j];
    float iz = g2a[o + 1024 + j] + g2b[o + 1024 + j] + qa[oq + 1024 + j] + qb[oq + 1024 + j] + bch[1024 + j];
    float in_= g2a[o + 2048 + j] + g2b[o + 2048 + j] + qa[oq + 2048 + j] + qb[oq + 2048 + j] + bch[2048 + j];
    float hr = gh2a[o + j]        + gh2b[o + j];
    float hz = gh2a[o + 1024 + j] + gh2b[o + 1024 + j];
    float hn = gh2a[o + 2048 + j] + gh2b[o + 2048 + j];
    float r = 1.f / (1.f + expf(-(ir + hr)));
    float z = 1.f / (1.f + expf(-(iz + hz)));
    float n = tanhf(in_ + r * hn);
    float hnew = (1.f - z) * n + z * h2[idx];
    h2[idx] = hnew;
    ushort_t hq = f2b(hnew);
    h2b[idx] = hq;
    H2Ab[((long)(b * TSTEP + t) << 10) | j] = hq;
}

// attention: q = relu(qa+qb+bcat2[0:1024]); logits=vw.q; softmax; alpha; att_v
__global__ __launch_bounds__(256) void attention_kernel(
    const float* __restrict__ qa, const float* __restrict__ qb,
    const float* __restrict__ bc,    // bcat2 (first 1024 used)
    const ushort_t* __restrict__ vwb, const float* __restrict__ v,
    const int* __restrict__ cap_len, int t,
    ushort_t* __restrict__ x2v, float* __restrict__ alpha)
{
    int b = blockIdx.x;
    __shared__ float q_s[HID];
    __shared__ float att_s[NOBJ];
    int tid = threadIdx.x;
    int lane = tid & 63, w = tid >> 6;
    long oq = (long)b * 4096;
    for (int i = tid; i < HID; i += 256)
        q_s[i] = fmaxf(qa[oq + i] + qb[oq + i] + bc[i], 0.f);
    __syncthreads();
    for (int o = w; o < NOBJ; o += 4) {
        const ushort_t* vwo = vwb + ((long)b * NOBJ + o) * HID;
        float s = 0.f;
        for (int hh = lane; hh < HID; hh += 64) s += b2f(vwo[hh]) * q_s[hh];
        for (int off = 32; off > 0; off >>= 1) s += __shfl_down(s, off);
        if (lane == 0) att_s[o] = s;
    }
    __syncthreads();
    if (tid == 0) {
        float mx = att_s[0];
        for (int o = 1; o < NOBJ; o++) mx = fmaxf(mx, att_s[o]);
        float sum = 0.f;
        for (int o = 0; o < NOBJ; o++) { float e = expf(att_s[o] - mx); att_s[o] = e; sum += e; }
        float inv = 1.f / sum;
        for (int o = 0; o < NOBJ; o++) att_s[o] *= inv;
    }
    __syncthreads();
    bool m = (t < cap_len[b] - 1);
    if (tid < NOBJ) alpha[((long)b * MAXLEN + t) * NOBJ + tid] = m ? att_s[tid] : 0.f;
    for (int d = tid; d < VDIM; d += 256) {
        float s = 0.f;
        for (int o = 0; o < NOBJ; o++)
            s += att_s[o] * v[((long)b * NOBJ + o) * VDIM + d];
        x2v[(long)b * VDIM + d] = f2b(s);
    }
}

// ---------------------------------------------------------------------------
// prologue / epilogue helpers (unchanged from round 2)
// ---------------------------------------------------------------------------
__global__ void init_kernel(const int* __restrict__ caption,
                            int* __restrict__ tok_idx, int* __restrict__ crow20,
                            float* __restrict__ h12f, ushort_t* __restrict__ h12b)
{
    int idx = blockIdx.x * 256 + threadIdx.x;
    if (idx < BATCH * TSTEP) {
        int b = idx / TSTEP, t = idx % TSTEP;
        tok_idx[idx] = caption[b * MAXLEN + t];
        crow20[idx]  = b * MAXLEN + t;
    }
    h12f[idx] = 0.f;
    h12b[idx] = 0;
}

__global__ void sort_caption_kernel(const int* __restrict__ caption,
                                    const int* __restrict__ cap_len,
                                    float* __restrict__ out1)
{
    int i = threadIdx.x;
    if (i < BATCH) {
        int li = cap_len[i];
        int rank = 0;
        for (int j = 0; j < BATCH; j++) {
            int lj = cap_len[j];
            if (lj > li || (lj == li && j < i)) rank++;
        }
        for (int k = 0; k < TSTEP; k++)
            out1[rank * TSTEP + k] = (float)caption[i * MAXLEN + 1 + k];
    }
}

__global__ void vmean_kernel(const float* __restrict__ v,
                             float* __restrict__ vmean, ushort_t* __restrict__ vmeanb)
{
    int idx = blockIdx.x * 256 + threadIdx.x;
    int b = idx >> 11, d = idx & (VDIM - 1);
    float s = 0.f;
    for (int o = 0; o < NOBJ; o++) s += v[((long)b * NOBJ + o) * VDIM + d];
    float m = s * (1.0f / 36.0f);
    vmean[idx] = m;
    vmeanb[idx] = f2b(m);
}

__global__ void conv_kernel(const float* __restrict__ src, long ld,
                            const int* __restrict__ rowidx,
                            ushort_t* __restrict__ dst, int rows, int cols)
{
    long idx4 = ((long)blockIdx.x * 256 + threadIdx.x) * 4;
    if (idx4 >= (long)rows * cols) return;
    int r = (int)(idx4 / cols);
    int c = (int)(idx4 % cols);
    long sr = rowidx ? rowidx[r] : r;
    float4 f = *(const float4*)(src + sr * ld + c);
    dst[idx4 + 0] = f2b(f.x);
    dst[idx4 + 1] = f2b(f.y);
    dst[idx4 + 2] = f2b(f.z);
    dst[idx4 + 3] = f2b(f.w);
}

__global__ void transpose_conv_kernel(const float* __restrict__ src,
                                      ushort_t* __restrict__ dst)
{
    __shared__ float tile[32][33];
    int bx = blockIdx.x, by = blockIdx.y;
    int lx = threadIdx.x & 31, ly = threadIdx.x >> 5;
    for (int i = 0; i < 32; i += 8)
        tile[ly + i][lx] = src[(long)(by * 32 + ly + i) * 1024 + bx * 32 + lx];
    __syncthreads();
    for (int i = 0; i < 32; i += 8)
        dst[(long)(bx * 32 + ly + i) * 1024 + by * 32 + lx] = f2b(tile[lx][ly + i]);
}

__global__ void bias_fold_kernel(const float* __restrict__ Wq,
                                 const float* __restrict__ Wih2,
                                 const float* __restrict__ bfc1,
                                 const float* __restrict__ bq,
                                 const float* __restrict__ bih2,
                                 float* __restrict__ bcat2)
{
    int wave = blockIdx.x * 4 + (threadIdx.x >> 6);
    int lane = threadIdx.x & 63;
    for (int n = wave; n < 4096; n += 256) {
        const float* wrow = (n < 1024) ? (Wq + (long)n * 1024)
                                       : (Wih2 + (long)(n - 1024) * 3072 + 2048);
        float s = 0.f;
        for (int j = lane; j < 1024; j += 64) s += wrow[j] * bfc1[j];
        for (int off = 32; off > 0; off >>= 1) s += __shfl_down(s, off);
        if (lane == 0) bcat2[n] = s + ((n < 1024) ? bq[n] : bih2[n - 1024]);
    }
}

__global__ __launch_bounds__(256) void softmax_kernel(float* __restrict__ predict,
                                                      float* __restrict__ alpha,
                                                      const int* __restrict__ cap_len)
{
    __shared__ float sred[4];
    int row = blockIdx.x;
    int b = row / MAXLEN, t = row % MAXLEN;
    float* p = predict + (long)row * NTOKEN;
    int tid = threadIdx.x;
    int dec = cap_len[b] - 1;
    if (t >= dec) {
        const float u = 1.0f / (float)NTOKEN;
        for (int i = tid; i < NTOKEN; i += 256) p[i] = u;
        if (t == MAXLEN - 1 && tid < NOBJ) alpha[(long)row * NOBJ + tid] = 0.f;
        return;
    }
    float mx = -3.4e38f;
    for (int i = tid; i < NTOKEN; i += 256) mx = fmaxf(mx, p[i]);
    for (int off = 32; off > 0; off >>= 1) mx = fmaxf(mx, __shfl_down(mx, off));
    if ((tid & 63) == 0) sred[tid >> 6] = mx;
    __syncthreads();
    mx = fmaxf(fmaxf(sred[0], sred[1]), fmaxf(sred[2], sred[3]));
    __syncthreads();
    float s = 0.f;
    for (int i = tid; i < NTOKEN; i += 256) s += expf(p[i] - mx);
    for (int off = 32; off > 0; off >>= 1) s += __shfl_down(s, off);
    if ((tid & 63) == 0) sred[tid >> 6] = s;
    __syncthreads();
    s = sred[0] + sred[1] + sred[2] + sred[3];
    float inv = 1.f / s;
    for (int i = tid; i < NTOKEN; i += 256) p[i] = expf(p[i] - mx) * inv;
}

// ---------------------------------------------------------------------------
extern "C" void kernel_launch(void* const* d_in, const int* in_sizes, int n_in,
                              void* d_out, int out_size, void* d_ws, size_t ws_size,
                              hipStream_t stream)
{
    const float* v       = (const float*)d_in[0];
    const int*   caption = (const int*)  d_in[1];
    const int*   cap_len = (const int*)  d_in[2];
    const float* emb     = (const float*)d_in[3];
    const float* Wih1    = (const float*)d_in[4];
    const float* Whh1    = (const float*)d_in[5];
    const float* bih1    = (const float*)d_in[6];
    const float* bhh1    = (const float*)d_in[7];
    const float* Wih2    = (const float*)d_in[8];
    const float* Whh2    = (const float*)d_in[9];
    const float* bih2    = (const float*)d_in[10];
    const float* bhh2    = (const float*)d_in[11];
    const float* Wfc1    = (const float*)d_in[12];
    const float* bfc1    = (const float*)d_in[13];
    const float* Wfc2    = (const float*)d_in[14];
    const float* bfc2    = (const float*)d_in[15];
    const float* Wv      = (const float*)d_in[16];
    const float* bv      = (const float*)d_in[17];
    const float* Wq      = (const float*)d_in[18];
    const float* bq      = (const float*)d_in[19];
    const float* Wa      = (const float*)d_in[20];
    // ba cancels in softmax

    float* f32base = (float*)d_ws;
    float* gvm   = f32base;              // 128*3072
    float* gi1s  = gvm   + 393216;       // 2432*3072
    float* h1    = gi1s  + 7471104;      // 128*1024 (h1,h2 contiguous for init)
    float* h2    = h1    + 131072;
    float* vmean = h2    + 131072;       // 128*2048
    float* bcat2 = vmean + 262144;       // 4096
    ushort_t* ub = (ushort_t*)(bcat2 + 4096);
    ushort_t* Wih1h = ub;                 // 3072*1024
    ushort_t* Wih1c = Wih1h + 3145728;
    ushort_t* Whh1b = Wih1c + 3145728;
    ushort_t* Whh2b = Whh1b + 3145728;
    ushort_t* Wih2v = Whh2b + 3145728;    // 3072*2048
    ushort_t* Wcat2 = Wih2v + 6291456;    // 4096*1024
    ushort_t* Wfc2b = Wcat2 + 4194304;    // 15000*1024
    ushort_t* vw_bf = Wfc2b + 15360000;   // 4608*1024
    ushort_t* H2Ab  = vw_bf + 4718592;    // 2432*1024
    ushort_t* h1b   = H2Ab  + 2490368;    // (h1b,h2b contiguous for init)
    ushort_t* h2b   = h1b   + 131072;
    ushort_t* x2v   = h2b   + 131072;     // 128*2048
    ushort_t* vmeanb= x2v   + 262144;     // 128*2048
    ushort_t* TEMP  = vmeanb+ 262144;     // 11534336 ushorts
    // prologue-only TEMP sub-uses:
    ushort_t* vb     = TEMP;              // 4608*2048
    ushort_t* Wvb    = TEMP + 9437184;    // 1024*2048
    ushort_t* Wqb    = TEMP;              // 1024*1024
    ushort_t* Wih2hb = TEMP + 1048576;    // 3072*1024
    ushort_t* Wfc1T  = TEMP + 4194304;    // 1024*1024
    ushort_t* Wih1m  = TEMP;              // 3072*2048
    ushort_t* Acap   = TEMP;              // 2432*1024
    // loop-time partial buffers alias TEMP (prologue done by then):
    float* part  = (float*)TEMP;          // 4194304 floats = 8388608 ushorts < 11534336
    float* gia   = part;                  // 128*3072
    float* gib   = gia  + 393216;
    float* gha   = gib  + 393216;
    float* ghb   = gha  + 393216;
    float* gh2a  = ghb  + 393216;
    float* gh2b  = gh2a + 393216;
    float* qgi2a = gh2b + 393216;         // 128*4096
    float* qgi2b = qgi2a + 524288;
    float* gi2a  = qgi2b + 524288;        // 128*3072
    float* gi2b  = gi2a + 393216;
    int* tok_idx = (int*)(TEMP + 11534336);
    int* crow20  = tok_idx + BATCH * TSTEP;

    float* out     = (float*)d_out;
    float* predict = out;                                   // 128*20*15000
    float* out1    = out + (long)BATCH * MAXLEN * NTOKEN;   // 128*19
    float* alpha   = out1 + (long)BATCH * TSTEP;            // 128*20*36

    #define CONV(src, ld, rowidx, dst, rows, cols) \
        conv_kernel<<<(int)(((long)(rows)*(cols)/4 + 255)/256), 256, 0, stream>>>( \
            src, ld, rowidx, dst, rows, cols)

    // ---- prologue ----
    init_kernel<<<1024, 256, 0, stream>>>(caption, tok_idx, crow20, h1, h1b);
    sort_caption_kernel<<<1, 128, 0, stream>>>(caption, cap_len, out1);
    vmean_kernel<<<(BATCH * VDIM) / 256, 256, 0, stream>>>(v, vmean, vmeanb);

    CONV(Wih1,        4096, nullptr, Wih1h, 3072, 1024);
    CONV(Wih1 + 3072, 4096, nullptr, Wih1c, 3072, 1024);
    CONV(Whh1,        1024, nullptr, Whh1b, 3072, 1024);
    CONV(Whh2,        1024, nullptr, Whh2b, 3072, 1024);
    CONV(Wih2,        3072, nullptr, Wih2v, 3072, 2048);
    CONV(Wfc2,        1024, nullptr, Wfc2b, NTOKEN, 1024);

    // vw = relu(v @ Wv^T + bv) * Wa -> bf16 [4608 x 1024]
    CONV(v,  2048, nullptr, vb,  4608, 2048);
    CONV(Wv, 2048, nullptr, Wvb, 1024, 2048);
    mfma_gemm<8, true><<<dim3(8, 36), 256, 0, stream>>>(
        vb, 2048, nullptr, Wvb, 2048, vw_bf, 1024, nullptr,
        bv, Wa, nullptr, 0, 1, 1024, 1024, 2048);

    // folded weights: Wcat2 = [Wq@Wfc1 ; Wih2[:,2048:]@Wfc1]
    CONV(Wq,          1024, nullptr, Wqb,    1024, 1024);
    CONV(Wih2 + 2048, 3072, nullptr, Wih2hb, 3072, 1024);
    transpose_conv_kernel<<<dim3(32, 32), 256, 0, stream>>>(Wfc1, Wfc1T);
    mfma_gemm<8, true><<<dim3(8, 8), 256, 0, stream>>>(
        Wqb, 1024, nullptr, Wfc1T, 1024, Wcat2, 1024, nullptr,
        nullptr, nullptr, nullptr, 0, 1, 0, 1024, 1024);
    mfma_gemm<8, true><<<dim3(8, 24), 256, 0, stream>>>(
        Wih2hb, 1024, nullptr, Wfc1T, 1024, Wcat2 + 1048576, 1024, nullptr,
        nullptr, nullptr, nullptr, 0, 1, 0, 1024, 1024);
    bias_fold_kernel<<<64, 256, 0, stream>>>(Wq, Wih2, bfc1, bq, bih2, bcat2);

    // gvm = vmean @ Wih1[:,1024:3072]^T + bih1
    CONV(Wih1 + 1024, 4096, nullptr, Wih1m, 3072, 2048);
    mfma_gemm<8, false><<<dim3(24, 1), 256, 0, stream>>>(
        vmeanb, 2048, nullptr, Wih1m, 2048, gvm, 3072, nullptr,
        bih1, nullptr, nullptr, 0, 1, 0, 3072, 2048);

    // gi1s[b*19+t] = emb[cap[b,t]] @ Wih1[:,3072:]^T + gvm[b]
    CONV(emb, 1024, tok_idx, Acap, 2432, 1024);
    mfma_gemm<8, false><<<dim3(24, 19), 256, 0, stream>>>(
        Acap, 1024, nullptr, Wih1c, 1024, gi1s, 3072, nullptr,
        nullptr, nullptr, gvm, 3072, TSTEP, 0, 3072, 1024);

    // ---- recurrent loop (6 small dispatches per step, split-K x2) ----
    for (int t = 0; t < TSTEP; t++) {
        trio_kernel<<<dim3(48, 2, 3), 256, 0, stream>>>(
            h1b, h2b, Wih1h, Whh1b, Whh2b,
            gia, gib, gha, ghb, gh2a, gh2b,
            gi1s + (long)t * 3072, bhh1, bhh2);
        gru1_kernel<<<512, 256, 0, stream>>>(gia, gib, gha, ghb, h1, h1b);
        qgi2_kernel<<<dim3(128, 2), 256, 0, stream>>>(h1b, Wcat2, qgi2a, qgi2b);
        attention_kernel<<<BATCH, 256, 0, stream>>>(
            qgi2a, qgi2b, bcat2, vw_bf, v, cap_len, t, x2v, alpha);
        gi2_kernel<<<dim3(96, 2), 256, 0, stream>>>(x2v, Wih2v, gi2a, gi2b);
        gru2_kernel<<<512, 256, 0, stream>>>(
            gi2a, gi2b, qgi2a, qgi2b, bcat2 + 1024, gh2a, gh2b,
            h2, h2b, H2Ab, t);
    }

    // ---- epilogue ----
    mfma_gemm<8, false><<<dim3(118, 19), 256, 0, stream>>>(
        H2Ab, 1024, nullptr, Wfc2b, 1024, predict, NTOKEN, crow20,
        bfc2, nullptr, nullptr, 0, 1, 0, NTOKEN, 1024);
    softmax_kernel<<<BATCH * MAXLEN, 256, 0, stream>>>(predict, alpha, cap_len);
    #undef CONV
}